// Round 8
// baseline (245.050 us; speedup 1.0000x reference)
//
#include <hip/hip_runtime.h>
#include <hip/hip_bf16.h>

// ScalarDistanceDeepSet: B=32, N=256, pairs P=32640 (upper tri, k=1)
// phi: s -> relu(s*W1+b1)[64] -> relu(.@W2+b2)[128], masked sum over pairs
// rho: pooled[128] -> 256 -> 128 -> 64
//
// g_e(s) is piecewise-linear in s with 64 shared breakpoints. Tables
// alpha/beta[seg][e] make per-(pair,channel) work 1 FMA + 1 max. EXACT.
//
// R8: fuse rho into phi (last-block-per-batch pattern): 2 launches instead
// of 3; rho overlaps other batches' phi tails. Last block re-reads pooled
// via device-scope atomic loads and stages W3/W4/W5 in halves through the
// reused table LDS. phi structure = R7 (float4 table, 66.5KB, 1024 thr,
// mirror-row balance, parity column split, ballot segment find).

#define NB 32
#define NN 256
#define PHI2 128
#define SEGS 65

// ---------------- Kernel A: build tables ----------------
// grid: 65 blocks (one per segment), 128 threads (one per output channel e)
// table4[seg][l] = {alpha[l], beta[l], alpha[l+64], beta[l+64]}
__global__ __launch_bounds__(128) void build_tables(
    const float* __restrict__ W1, const float* __restrict__ b1,
    const float* __restrict__ W2, const float* __restrict__ b2,
    float4* __restrict__ table4,   // [SEGS][64]
    float* __restrict__ tsort, float* __restrict__ pooled,
    int* __restrict__ ctr) {
  __shared__ float w2_s[64 * PHI2];   // 32 KB
  __shared__ float t_s[64], w1_s[64], b1_s[64];
  __shared__ float a_sh[128], b_sh[128];
  __shared__ int cat_s[64], rank_s[64];
  const int tid = threadIdx.x;
  const int seg = blockIdx.x;
  const float4* W2v = (const float4*)W2;
  float4* w2v = (float4*)w2_s;
  for (int i = tid; i < 64 * PHI2 / 4; i += 128) w2v[i] = W2v[i];
  if (tid < 64) {
    float w = W1[tid], bb = b1[tid];
    w1_s[tid] = w; b1_s[tid] = bb;
    int cat; float t;
    if (w > 0.f)      { cat = 0; t = -bb / w; }   // active for s > t
    else if (w < 0.f) { cat = 1; t = -bb / w; }   // active for s < t
    else              { cat = (bb > 0.f) ? 2 : 3; t = 0.f; } // always/never
    t_s[tid] = t; cat_s[tid] = cat;
  }
  __syncthreads();
  if (tid < 64) {
    float t = t_s[tid]; int r = 0;
    for (int k = 0; k < 64; ++k) {
      float tk = t_s[k];
      r += (tk < t) || (tk == t && k < tid);   // stable rank
    }
    rank_s[tid] = r;
    if (seg == 0) tsort[r] = t;
  }
  __syncthreads();
  // channel e = tid. seg(s) = #breakpoints strictly < s.
  float a = 0.f, bsum = b2[tid];
#pragma unroll 8
  for (int j = 0; j < 64; ++j) {
    int cat = cat_s[j], r = rank_s[j];
    bool act = (cat == 0) ? (seg > r) : (cat == 1) ? (seg <= r) : (cat == 2);
    float w2 = w2_s[j * PHI2 + tid];
    float m = act ? 1.f : 0.f;
    a    = fmaf(m * w1_s[j], w2, a);
    bsum = fmaf(m * b1_s[j], w2, bsum);
  }
  a_sh[tid] = a; b_sh[tid] = bsum;
  __syncthreads();
  if (tid < 64)
    table4[seg * 64 + tid] =
        make_float4(a_sh[tid], b_sh[tid], a_sh[tid + 64], b_sh[tid + 64]);
  if (seg == 0) {
    for (int i = tid; i < NB * PHI2; i += 128) pooled[i] = 0.f;
    if (tid < NB) ctr[tid] = 0;
  }
}

// One pair visit, all 128 channels: broadcast s from lane L (uniform SGPR),
// segment via ballot over register-held breakpoints, one ds_read_b128.
__device__ __forceinline__ void visit(float comp, int L, float tv, int lane,
                                      const float4* ab_s, float& acc0,
                                      float& acc1) {
  float s = __int_as_float(__builtin_amdgcn_readlane(__float_as_int(comp), L));
  int pos = (int)__popcll(__ballot(tv < s));
  float4 p = ab_s[pos * 64 + lane];
  acc0 += fmaxf(fmaf(p.x, s, p.y), 0.f);
  acc1 += fmaxf(fmaf(p.z, s, p.w), 0.f);
}

// Dynamic-component visit for ragged row edges.
__device__ __forceinline__ void visit_dyn(const float4& f4, int j, float tv,
                                          int lane, const float4* ab_s,
                                          float& acc0, float& acc1) {
  int c = j & 3;
  float comp = (c == 0) ? f4.x : (c == 1) ? f4.y : (c == 2) ? f4.z : f4.w;
  visit(comp, j >> 2, tv, lane, ab_s, acc0, acc1);
}

// Process one row: f4 holds the full 256-float row across the wave (lane
// holds cols 4*lane..4*lane+3). Valid cols j in [i0+1, len-1]. This wave
// handles only column 4-groups with parity == half.
__device__ __forceinline__ void do_row(const float4& f4, int i0, int len,
                                       int half, float tv, int lane,
                                       const float4* ab_s, float& acc0,
                                       float& acc1) {
  const int jlo = i0 + 1, jhi = len - 1;   // inclusive; jhi >= jlo guaranteed
  const int fullLo = (jlo + 3) >> 2;       // first fully-valid 4-group
  const int fullHi = (jhi >= 3) ? ((jhi - 3) >> 2) : -1;  // last fully-valid
  if (fullLo > fullHi) {
    for (int j = jlo; j <= jhi; ++j)
      if (((j >> 2) & 1) == half) visit_dyn(f4, j, tv, lane, ab_s, acc0, acc1);
    return;
  }
  for (int j = jlo; j < fullLo * 4; ++j)
    if (((j >> 2) & 1) == half) visit_dyn(f4, j, tv, lane, ab_s, acc0, acc1);
  int L0 = fullLo + (((fullLo & 1) != half) ? 1 : 0);
#pragma unroll 2
  for (int L = L0; L <= fullHi; L += 2) {
    visit(f4.x, L, tv, lane, ab_s, acc0, acc1);
    visit(f4.y, L, tv, lane, ab_s, acc0, acc1);
    visit(f4.z, L, tv, lane, ab_s, acc0, acc1);
    visit(f4.w, L, tv, lane, ab_s, acc0, acc1);
  }
  for (int j = fullHi * 4 + 4; j <= jhi; ++j)
    if (((j >> 2) & 1) == half) visit_dyn(f4, j, tv, lane, ab_s, acc0, acc1);
}

// ---------------- Kernel B: phi + pooling + fused rho ----------------
// grid: (16, 32 batches) x 1024 threads (16 waves). c_row = x>>1 (rows
// c_row*16+w plus mirrors), half = x&1 (column-group parity). After the
// pooled atomics, blocks bump ctr[b]; the 16th block for batch b runs the
// rho MLP inline, staging weight layers in halves through the reused
// table LDS (16640 floats >= 16384-float half-layers).
__global__ __launch_bounds__(1024, 8) void phi_pool_rho(
    const float* __restrict__ dm, const int* __restrict__ lengths,
    const float4* __restrict__ table4, const float* __restrict__ tsort,
    float* __restrict__ pooled, int* __restrict__ ctr,
    const float* __restrict__ W3, const float* __restrict__ b3,
    const float* __restrict__ W4, const float* __restrict__ b4,
    const float* __restrict__ W5, const float* __restrict__ b5,
    float* __restrict__ out) {
  __shared__ float4 ab_s[SEGS * 64];   // 66,560 B (reused by rho staging)
  __shared__ float p_s[128], r1_s[256], r2_s[128];
  __shared__ int lastflag;
  const int c_row = blockIdx.x >> 1;
  const int half  = blockIdx.x & 1;
  const int b     = blockIdx.y;   // batch
  const int tid = threadIdx.x;
  const int lane = tid & 63, w = tid >> 6;

  const int len = lengths[b];
  // block-uniform: does this block have any pairs?
  const bool work = !(c_row * 16 > len - 2 && 239 - c_row * 16 > len - 2);

  if (work) {
    for (int i = tid; i < SEGS * 64; i += 1024) ab_s[i] = table4[i];
    __syncthreads();

    const float tv = tsort[lane];    // breakpoint in register, one per lane
    const float* dmb = dm + (size_t)b * (NN * NN);
    float acc0 = 0.f, acc1 = 0.f;

    const int rA = c_row * 16 + w;   // 0..127
    const int rB = 254 - rA;         // 127..254
    const float4 fA = ((const float4*)(dmb + rA * NN))[lane];
    const float4 fB = ((const float4*)(dmb + rB * NN))[lane];
    if (rA <= len - 2) do_row(fA, rA, len, half, tv, lane, ab_s, acc0, acc1);
    if (rB != rA && rB <= len - 2)
      do_row(fB, rB, len, half, tv, lane, ab_s, acc0, acc1);

    atomicAdd(&pooled[b * PHI2 + lane], acc0);
    atomicAdd(&pooled[b * PHI2 + 64 + lane], acc1);
  }

  // ---- last-block-per-batch handoff ----
  __threadfence();
  if (tid == 0) lastflag = (atomicAdd(&ctr[b], 1) == 15);
  __syncthreads();
  if (!lastflag) return;

  // coherent re-read of pooled (device-scope atomic load)
  if (tid < 128) p_s[tid] = atomicAdd(&pooled[b * PHI2 + tid], 0.0f);

  float* wbuf = (float*)ab_s;          // 16640-float staging buffer
  float4* wbv = (float4*)wbuf;

  // ---- layer 1: 128 -> 256 (W3 staged in 2 row-halves of 16384) ----
  float acc = (tid < 256) ? b3[tid] : 0.f;
  {
    const float4* w3v = (const float4*)W3;
    __syncthreads();
    for (int i = tid; i < 4096; i += 1024) wbv[i] = w3v[i];        // rows 0-63
    __syncthreads();
    if (tid < 256) {
#pragma unroll 8
      for (int k = 0; k < 64; ++k) acc = fmaf(p_s[k], wbuf[k * 256 + tid], acc);
    }
    __syncthreads();
    for (int i = tid; i < 4096; i += 1024) wbv[i] = w3v[4096 + i]; // rows 64-127
    __syncthreads();
    if (tid < 256) {
#pragma unroll 8
      for (int k = 0; k < 64; ++k)
        acc = fmaf(p_s[64 + k], wbuf[k * 256 + tid], acc);
      r1_s[tid] = fmaxf(acc, 0.f);
    }
  }
  // ---- layer 2: 256 -> 128 (W4 staged in 2 row-halves of 16384) ----
  {
    const float4* w4v = (const float4*)W4;
    __syncthreads();
    for (int i = tid; i < 4096; i += 1024) wbv[i] = w4v[i];        // rows 0-127
    __syncthreads();
    float a2 = (tid < 128) ? b4[tid] : 0.f;
    if (tid < 128) {
#pragma unroll 8
      for (int k = 0; k < 128; ++k)
        a2 = fmaf(r1_s[k], wbuf[k * 128 + tid], a2);
    }
    __syncthreads();
    for (int i = tid; i < 4096; i += 1024) wbv[i] = w4v[4096 + i]; // rows 128-255
    __syncthreads();
    if (tid < 128) {
#pragma unroll 8
      for (int k = 0; k < 128; ++k)
        a2 = fmaf(r1_s[128 + k], wbuf[k * 128 + tid], a2);
      r2_s[tid] = fmaxf(a2, 0.f);
    }
  }
  // ---- layer 3: 128 -> 64 (W5 = 8192 floats, single stage) ----
  {
    const float4* w5v = (const float4*)W5;
    __syncthreads();
    for (int i = tid; i < 2048; i += 1024) wbv[i] = w5v[i];
    __syncthreads();
    if (tid < 64) {
      float a3 = b5[tid];
#pragma unroll 8
      for (int k = 0; k < 128; ++k) a3 = fmaf(r2_s[k], wbuf[k * 64 + tid], a3);
      out[b * 64 + tid] = a3;
    }
  }
}

extern "C" void kernel_launch(void* const* d_in, const int* in_sizes, int n_in,
                              void* d_out, int out_size, void* d_ws, size_t ws_size,
                              hipStream_t stream) {
  const float* dm      = (const float*)d_in[0];
  const int*   lengths = (const int*)d_in[1];
  const float* W1 = (const float*)d_in[2];
  const float* b1 = (const float*)d_in[3];
  const float* W2 = (const float*)d_in[4];
  const float* b2 = (const float*)d_in[5];
  const float* W3 = (const float*)d_in[6];
  const float* b3 = (const float*)d_in[7];
  const float* W4 = (const float*)d_in[8];
  const float* b4 = (const float*)d_in[9];
  const float* W5 = (const float*)d_in[10];
  const float* b5 = (const float*)d_in[11];

  float* ws = (float*)d_ws;
  float4* table4 = (float4*)ws;          // 65*64 float4 = 16640 floats
  float* tsort   = ws + 16640;           // 64
  float* pooled  = ws + 16704;           // 32*128 = 4096
  int*   ctr     = (int*)(ws + 20800);   // 32

  build_tables<<<SEGS, 128, 0, stream>>>(W1, b1, W2, b2, table4, tsort,
                                         pooled, ctr);
  phi_pool_rho<<<dim3(16, NB), 1024, 0, stream>>>(
      dm, lengths, table4, tsort, pooled, ctr,
      W3, b3, W4, b4, W5, b5, (float*)d_out);
}

// Round 9
// 132.925 us; speedup vs baseline: 1.8435x; 1.8435x over previous
//
#include <hip/hip_runtime.h>
#include <hip/hip_bf16.h>

// ScalarDistanceDeepSet: B=32, N=256, pairs P=32640 (upper tri, k=1)
// phi: s -> relu(s*W1+b1)[64] -> relu(.@W2+b2)[128], masked sum over pairs
// rho: pooled[128] -> 256 -> 128 -> 64
//
// g_e(s) is piecewise-linear in s with 64 shared breakpoints. Tables
// alpha/beta[seg][e] make per-(pair,channel) work 1 FMA + 1 max. EXACT.
//
// R9 = revert to R6 (best: 132.39us). R8's last-block fusion regressed to
// 245us: __threadfence() (device-scope) in all 8192 waves + launch_bounds
// register clamp (VGPR 20 -> scratch spills). Keeping the 3-kernel split:
// half-table (33.3KB) phi at 32 waves/CU, mirror-row balance, full-row
// float4 loads, ballot segment find; LDS-staged build_tables and rho_mlp.

#define NB 32
#define NN 256
#define PHI2 128
#define SEGS 65

// ---------------- Kernel A: build tables ----------------
// grid: 65 blocks (one per segment), 128 threads (one per output channel e)
// table2[h][seg][l] = {alpha, beta} for channel h*64+l
__global__ __launch_bounds__(128) void build_tables(
    const float* __restrict__ W1, const float* __restrict__ b1,
    const float* __restrict__ W2, const float* __restrict__ b2,
    float2* __restrict__ table2,   // [2][SEGS][64]
    float* __restrict__ tsort, float* __restrict__ pooled) {
  __shared__ float w2_s[64 * PHI2];   // 32 KB
  __shared__ float t_s[64], w1_s[64], b1_s[64];
  __shared__ int cat_s[64], rank_s[64];
  const int tid = threadIdx.x;
  const int seg = blockIdx.x;
  const float4* W2v = (const float4*)W2;
  float4* w2v = (float4*)w2_s;
  for (int i = tid; i < 64 * PHI2 / 4; i += 128) w2v[i] = W2v[i];
  if (tid < 64) {
    float w = W1[tid], bb = b1[tid];
    w1_s[tid] = w; b1_s[tid] = bb;
    int cat; float t;
    if (w > 0.f)      { cat = 0; t = -bb / w; }   // active for s > t
    else if (w < 0.f) { cat = 1; t = -bb / w; }   // active for s < t
    else              { cat = (bb > 0.f) ? 2 : 3; t = 0.f; } // always/never
    t_s[tid] = t; cat_s[tid] = cat;
  }
  __syncthreads();
  if (tid < 64) {
    float t = t_s[tid]; int r = 0;
    for (int k = 0; k < 64; ++k) {
      float tk = t_s[k];
      r += (tk < t) || (tk == t && k < tid);   // stable rank
    }
    rank_s[tid] = r;
    if (seg == 0) tsort[r] = t;
  }
  __syncthreads();
  // channel e = tid. seg(s) = #breakpoints strictly < s.
  float a = 0.f, bsum = b2[tid];
#pragma unroll 8
  for (int j = 0; j < 64; ++j) {
    int cat = cat_s[j], r = rank_s[j];
    bool act = (cat == 0) ? (seg > r) : (cat == 1) ? (seg <= r) : (cat == 2);
    float w2 = w2_s[j * PHI2 + tid];
    float m = act ? 1.f : 0.f;
    a    = fmaf(m * w1_s[j], w2, a);
    bsum = fmaf(m * b1_s[j], w2, bsum);
  }
  const int h = tid >> 6, l = tid & 63;
  table2[((h * SEGS) + seg) * 64 + l] = make_float2(a, bsum);
  if (seg == 0) {
    for (int i = tid; i < NB * PHI2; i += 128) pooled[i] = 0.f;
  }
}

// One (pair, channel) visit: broadcast s from lane L (uniform), segment via
// ballot over register-held sorted breakpoints, one contiguous ds_read_b64.
__device__ __forceinline__ void visit(float comp, int L, float tv, int lane,
                                      const float2* ab_s, float& acc) {
  float s = __int_as_float(__builtin_amdgcn_readlane(__float_as_int(comp), L));
  int pos = (int)__popcll(__ballot(tv < s));
  float2 p = ab_s[pos * 64 + lane];
  acc += fmaxf(fmaf(p.x, s, p.y), 0.f);
}

// Dynamic-component visit for ragged row edges (<=6 per row).
__device__ __forceinline__ void visit_dyn(const float4& f4, int j, float tv,
                                          int lane, const float2* ab_s,
                                          float& acc) {
  int c = j & 3;
  float comp = (c == 0) ? f4.x : (c == 1) ? f4.y : (c == 2) ? f4.z : f4.w;
  visit(comp, j >> 2, tv, lane, ab_s, acc);
}

// Process one row: f4 holds the full 256-float row across the wave
// (lane holds cols 4*lane..4*lane+3). Valid cols j in [i0+1, len-1].
__device__ __forceinline__ void do_row(const float4& f4, int i0, int len,
                                       float tv, int lane,
                                       const float2* ab_s, float& acc) {
  const int jlo = i0 + 1, jhi = len - 1;   // inclusive; jhi >= jlo guaranteed
  const int fullLo = (jlo + 3) >> 2;       // first fully-valid 4-group
  const int fullHi = (jhi >= 3) ? ((jhi - 3) >> 2) : -1;  // last fully-valid
  if (fullLo > fullHi) {
    for (int j = jlo; j <= jhi; ++j) visit_dyn(f4, j, tv, lane, ab_s, acc);
    return;
  }
  // low ragged edge
  for (int j = jlo; j < fullLo * 4; ++j) visit_dyn(f4, j, tv, lane, ab_s, acc);
  // interior full groups: uniform L in SGPR, static components
#pragma unroll 4
  for (int L = fullLo; L <= fullHi; ++L) {
    visit(f4.x, L, tv, lane, ab_s, acc);
    visit(f4.y, L, tv, lane, ab_s, acc);
    visit(f4.z, L, tv, lane, ab_s, acc);
    visit(f4.w, L, tv, lane, ab_s, acc);
  }
  // high ragged edge
  for (int j = fullHi * 4 + 4; j <= jhi; ++j)
    visit_dyn(f4, j, tv, lane, ab_s, acc);
}

// ---------------- Kernel B: phi + masked pooling ----------------
// grid: (16 row-chunks, 2 halves, 32 batches) x 512 threads (8 waves).
// Wave w owns row r = chunk*8+w (0..127) and its mirror 254-r (balanced).
__global__ __launch_bounds__(512, 8) void phi_pool(
    const float* __restrict__ dm, const int* __restrict__ lengths,
    const float2* __restrict__ table2, const float* __restrict__ tsort,
    float* __restrict__ pooled) {
  __shared__ float2 ab_s[SEGS * 64];   // 33,280 B -> 4 blocks/CU
  const int chunk = blockIdx.x;   // 0..15
  const int h     = blockIdx.y;   // channel half
  const int b     = blockIdx.z;   // batch
  const int tid = threadIdx.x;
  const int lane = tid & 63, w = tid >> 6;

  const int len = lengths[b];
  // block-uniform early exit: no primary row (8c) and no mirror row (247-8c)
  if (8 * chunk > len - 2 && 247 - 8 * chunk > len - 2) return;

  const float2* tg = table2 + h * SEGS * 64;
  for (int i = tid; i < SEGS * 64; i += 512) ab_s[i] = tg[i];
  __syncthreads();

  const float tv = tsort[lane];      // breakpoint in register, one per lane
  const float* dmb = dm + (size_t)b * (NN * NN);
  float acc = 0.f;

  const int rA = chunk * 8 + w;      // 0..127
  const int rB = 254 - rA;           // 127..254
  // issue both full-row loads up-front (always address-valid)
  const float4 fA = ((const float4*)(dmb + rA * NN))[lane];
  const float4 fB = ((const float4*)(dmb + rB * NN))[lane];
  if (rA <= len - 2) do_row(fA, rA, len, tv, lane, ab_s, acc);
  if (rB != rA && rB <= len - 2) do_row(fB, rB, len, tv, lane, ab_s, acc);

  atomicAdd(&pooled[b * PHI2 + h * 64 + lane], acc);
}

// ---------------- Kernel C: rho MLP ----------------
// grid: 32 blocks (one per batch), 256 threads. Weight layers staged
// through one reused 128 KB LDS buffer with independent float4 loads.
__global__ __launch_bounds__(256) void rho_mlp(
    const float* __restrict__ pooled,
    const float* __restrict__ W3, const float* __restrict__ b3,
    const float* __restrict__ W4, const float* __restrict__ b4,
    const float* __restrict__ W5, const float* __restrict__ b5,
    float* __restrict__ out) {
  __shared__ float w_s[128 * 256];     // 128 KB, reused per layer
  __shared__ float p_s[128], r1_s[256], r2_s[128];
  const int b = blockIdx.x, tid = threadIdx.x;
  float4* wsv = (float4*)w_s;
  {
    const float4* w3v = (const float4*)W3;
    for (int i = tid; i < 8192; i += 256) wsv[i] = w3v[i];
  }
  if (tid < 128) p_s[tid] = pooled[b * 128 + tid];
  __syncthreads();
  {
    float acc = b3[tid];
#pragma unroll 8
    for (int k = 0; k < 128; ++k) acc = fmaf(p_s[k], w_s[k * 256 + tid], acc);
    r1_s[tid] = fmaxf(acc, 0.f);
  }
  __syncthreads();
  {
    const float4* w4v = (const float4*)W4;
    for (int i = tid; i < 8192; i += 256) wsv[i] = w4v[i];
  }
  __syncthreads();
  if (tid < 128) {
    float acc = b4[tid];
#pragma unroll 8
    for (int k = 0; k < 256; ++k) acc = fmaf(r1_s[k], w_s[k * 128 + tid], acc);
    r2_s[tid] = fmaxf(acc, 0.f);
  }
  __syncthreads();
  {
    const float4* w5v = (const float4*)W5;
    for (int i = tid; i < 2048; i += 256) wsv[i] = w5v[i];
  }
  __syncthreads();
  if (tid < 64) {
    float acc = b5[tid];
#pragma unroll 8
    for (int k = 0; k < 128; ++k) acc = fmaf(r2_s[k], w_s[k * 64 + tid], acc);
    out[b * 64 + tid] = acc;
  }
}

extern "C" void kernel_launch(void* const* d_in, const int* in_sizes, int n_in,
                              void* d_out, int out_size, void* d_ws, size_t ws_size,
                              hipStream_t stream) {
  const float* dm      = (const float*)d_in[0];
  const int*   lengths = (const int*)d_in[1];
  const float* W1 = (const float*)d_in[2];
  const float* b1 = (const float*)d_in[3];
  const float* W2 = (const float*)d_in[4];
  const float* b2 = (const float*)d_in[5];
  const float* W3 = (const float*)d_in[6];
  const float* b3 = (const float*)d_in[7];
  const float* W4 = (const float*)d_in[8];
  const float* b4 = (const float*)d_in[9];
  const float* W5 = (const float*)d_in[10];
  const float* b5 = (const float*)d_in[11];

  float* ws = (float*)d_ws;
  float2* table2 = (float2*)ws;          // 2*65*64 float2 = 16640 floats
  float* tsort   = ws + 16640;           // 64
  float* pooled  = ws + 16704;           // 32*128 = 4096

  build_tables<<<SEGS, 128, 0, stream>>>(W1, b1, W2, b2, table2, tsort, pooled);
  phi_pool<<<dim3(16, 2, NB), 512, 0, stream>>>(dm, lengths, table2, tsort, pooled);
  rho_mlp<<<NB, 256, 0, stream>>>(pooled, W3, b3, W4, b4, W5, b5, (float*)d_out);
}